// Round 8
// baseline (359.386 us; speedup 1.0000x reference)
//
#include <hip/hip_runtime.h>
#include <hip/hip_fp16.h>
#include <hip/hip_cooperative_groups.h>

namespace cg = cooperative_groups;

typedef unsigned short u16;
typedef unsigned int u32;
typedef unsigned long long u64;
typedef float f32x4 __attribute__((ext_vector_type(4)));
typedef u32  u32x2 __attribute__((ext_vector_type(2)));

#define B_      64
#define C_      512
#define NN      576        // 24*24 nodes
#define NROW    24
#define THREADS 1024       // 16 waves
#define GRID    512        // 2 blocks/CU, all co-resident (cooperative)

__device__ __forceinline__ float bl(u32 u) {            // low bf16 -> f32
    union { u32 i; float f; } v; v.i = u << 16; return v.f;
}
__device__ __forceinline__ float bh(u32 u) {            // high bf16 -> f32
    union { u32 i; float f; } v; v.i = u & 0xFFFF0000u; return v.f;
}
__device__ __forceinline__ u16 f2b(float f) {           // f32 -> bf16 RNE
    union { float f; u32 i; } v; v.f = f;
    u32 x = v.i;
    x += 0x7fffu + ((x >> 16) & 1u);
    return (u16)(x >> 16);
}
__device__ __forceinline__ u16 f2h(float f) {           // f32 -> f16 RNE
    union { __half h; u16 u; } v; v.h = __float2half(f); return v.u;
}
__device__ __forceinline__ float h2f(u16 u) {           // f16 -> f32
    union { u16 u; __half h; } v; v.u = u; return __half2float(v.h);
}

template<bool BF>
__device__ __forceinline__ float dec(u16 u) {
    return BF ? bl((u32)u) : h2f(u);
}
template<bool BF>
__device__ __forceinline__ float4 dec4(const u16* p) {  // p 8B-aligned
    const uint2 u = *(const uint2*)p;
    if (BF) return make_float4(bl(u.x), bh(u.x), bl(u.y), bh(u.y));
    return make_float4(h2f((u16)(u.x & 0xFFFFu)), h2f((u16)(u.x >> 16)),
                       h2f((u16)(u.y & 0xFFFFu)), h2f((u16)(u.y >> 16)));
}

// 1/deg of grid node (r,c); deg in {2,3,4}. 1.0f/3.0f bit-matches the
// reference's float64->float32 cast, so geometric coefs are EXACT vs adj.
__device__ __forceinline__ float rdeg(int r, int c) {
    const int d = (r > 0) + (r < NROW - 1) + (c > 0) + (c < NROW - 1);
    return d == 4 ? 0.25f : (d == 3 ? (1.0f / 3.0f) : 0.5f);
}

// v8 (cooperative): block b owns 64 CONTIGUOUS rows [64b, 64b+64) of the
// linear (plane,channel) row space — one 147 KB linear slab of x and out
// (vs r4-r7's 64-way scatter of 2304-B chunks strided 1.18 MB, which halved
// effective BW and doubled WRITE_SIZE). Rows of block b = plane b/8,
// channels 64*(b%8)..+64. y kept packed-fp16 in registers across a grid
// sync; BN stats via 4 KB of global atomics + grid.sync().
template<bool BF>
__global__ __launch_bounds__(THREADS, 8) void fused_v8(
        const void* __restrict__ xv, const void* __restrict__ weight,
        const void* __restrict__ gamma, const void* __restrict__ beta,
        void* __restrict__ outv, float* __restrict__ ws) {
    __shared__ __align__(16) u16 xs[64 * NN];   // 73,728 B: [lrow][node]
    __shared__ float sst[128];                  // 64 scale + 64 shift
    cg::grid_group grid = cg::this_grid();
    const int t = threadIdx.x, b = blockIdx.x;
    const int wave = t >> 6, lane = t & 63;
    const int cbase = (b & 7) << 6;             // this block's channel base
    const u64 rbase = (u64)b << 6;              // first global row

    if (t < 2) ws[t * C_ + b] = 0.f;            // zero own channel's slot

    // ---- stage 64 contiguous rows: fully linear coalesced global read ----
    if (BF) {
        const u16* xb = (const u16*)xv + rbase * NN;
        #pragma unroll
        for (int k = 0; k < 5; ++k) {
            const int g = t + THREADS * k;      // 16-B chunk, 4608 total
            if (g < 4608) *(uint4*)(xs + 8 * g) = *(const uint4*)(xb + 8 * g);
        }
    } else {
        const float* xf = (const float*)xv + rbase * NN;
        #pragma unroll
        for (int k = 0; k < 9; ++k) {
            const int g = t + THREADS * k;      // 16-B chunk, 9216 total
            const float4 v = *(const float4*)(xf + 4 * g);
            uint2 pk;
            pk.x = (u32)f2h(v.x) | ((u32)f2h(v.y) << 16);
            pk.y = (u32)f2h(v.z) | ((u32)f2h(v.w) << 16);
            *(uint2*)(xs + 4 * g) = pk;
        }
    }
    __syncthreads();

    // ---- stencil: wave handles local rows 4w..4w+3 (distinct channels) ----
    float s0 = 0.f, s1 = 0.f, sA2 = 0.f, sB2 = 0.f;  // per-row stats (q=0..3)
    float s2_ = 0.f, s3 = 0.f, sC2 = 0.f, sD2 = 0.f;
    uint2 Y[3][4];                              // 24 VGPRs packed-fp16 y
    #pragma unroll
    for (int i = 0; i < 3; ++i) {
        const int L = lane + 64 * i;
        if (L < 144) {
            const int n = 4 * L;
            const int r = n / NROW, c0 = n - r * NROW;
            float4 cu, cd, cl, cr;
            {
                const bool up = r > 0, dn = r < NROW - 1;
                cu.x = up ? rdeg(r - 1, c0)     : 0.f;
                cu.y = up ? rdeg(r - 1, c0 + 1) : 0.f;
                cu.z = up ? rdeg(r - 1, c0 + 2) : 0.f;
                cu.w = up ? rdeg(r - 1, c0 + 3) : 0.f;
                cd.x = dn ? rdeg(r + 1, c0)     : 0.f;
                cd.y = dn ? rdeg(r + 1, c0 + 1) : 0.f;
                cd.z = dn ? rdeg(r + 1, c0 + 2) : 0.f;
                cd.w = dn ? rdeg(r + 1, c0 + 3) : 0.f;
                cl.x = (c0 > 0) ? rdeg(r, c0 - 1) : 0.f;
                cl.y = rdeg(r, c0);
                cl.z = rdeg(r, c0 + 1);
                cl.w = rdeg(r, c0 + 2);
                cr.x = rdeg(r, c0 + 1);
                cr.y = rdeg(r, c0 + 2);
                cr.z = rdeg(r, c0 + 3);
                cr.w = (c0 + 3 < NROW - 1) ? rdeg(r, c0 + 4) : 0.f;
            }
            const int nu = (r > 0)        ? n - NROW : n;
            const int nd = (r < NROW - 1) ? n + NROW : n;
            const int il = (c0 > 0)       ? n - 1    : 0;
            const int ir = (n + 4 < NN)   ? n + 4    : 0;
            #pragma unroll
            for (int q = 0; q < 4; ++q) {
                const int lrow = 4 * wave + q;
                const u16* xp = xs + lrow * NN;
                const float4 xc = dec4<BF>(xp + n);
                const float4 xu = dec4<BF>(xp + nu);
                const float4 xd = dec4<BF>(xp + nd);
                const float xlm = dec<BF>(xp[il]);
                const float xrp = dec<BF>(xp[ir]);
                float4 wv;                      // per-row weight (L2-resident)
                if (BF) {
                    const uint2 u = *(const uint2*)((const u16*)weight
                                    + (u64)(cbase + lrow) * NN + n);
                    wv = make_float4(bl(u.x), bh(u.x), bl(u.y), bh(u.y));
                } else {
                    wv = *(const float4*)((const float*)weight
                                    + (u64)(cbase + lrow) * NN + n);
                }
                const float y0 = (xc.x + cu.x*xu.x + cd.x*xd.x + cl.x*xlm  + cr.x*xc.y) * wv.x;
                const float y1 = (xc.y + cu.y*xu.y + cd.y*xd.y + cl.y*xc.x + cr.y*xc.z) * wv.y;
                const float y2 = (xc.z + cu.z*xu.z + cd.z*xd.z + cl.z*xc.y + cr.z*xc.w) * wv.z;
                const float y3 = (xc.w + cu.w*xu.w + cd.w*xd.w + cl.w*xc.z + cr.w*xrp ) * wv.w;
                const float ssum = (y0 + y1) + (y2 + y3);
                float ssq = y0 * y0;
                ssq = fmaf(y1, y1, ssq); ssq = fmaf(y2, y2, ssq);
                ssq = fmaf(y3, y3, ssq);
                if (q == 0) { s0 += ssum; sA2 += ssq; }
                if (q == 1) { s1 += ssum; sB2 += ssq; }
                if (q == 2) { s2_ += ssum; sC2 += ssq; }
                if (q == 3) { s3 += ssum; sD2 += ssq; }
                Y[i][q].x = (u32)f2h(y0) | ((u32)f2h(y1) << 16);
                Y[i][q].y = (u32)f2h(y2) | ((u32)f2h(y3) << 16);
            }
        }
    }
    // per-row reduction across the wave (each row = one channel)
    #pragma unroll
    for (int o = 32; o; o >>= 1) {
        s0  += __shfl_xor(s0,  o, 64); sA2 += __shfl_xor(sA2, o, 64);
        s1  += __shfl_xor(s1,  o, 64); sB2 += __shfl_xor(sB2, o, 64);
        s2_ += __shfl_xor(s2_, o, 64); sC2 += __shfl_xor(sC2, o, 64);
        s3  += __shfl_xor(s3,  o, 64); sD2 += __shfl_xor(sD2, o, 64);
    }

    grid.sync();                                // all zero-inits visible
    if (lane == 0) {
        const int c = cbase + 4 * wave;
        atomicAdd(&ws[c + 0], s0);  atomicAdd(&ws[C_ + c + 0], sA2);
        atomicAdd(&ws[c + 1], s1);  atomicAdd(&ws[C_ + c + 1], sB2);
        atomicAdd(&ws[c + 2], s2_); atomicAdd(&ws[C_ + c + 2], sC2);
        atomicAdd(&ws[c + 3], s3);  atomicAdd(&ws[C_ + c + 3], sD2);
    }
    grid.sync();                                // all stats complete

    // ---- finalize scale/shift for this block's 64 channels ----
    if (t < 64) {
        const int c = cbase + t;
        const float cnt = (float)(B_ * NN);
        const float m = ws[c] / cnt;
        const float v = ws[C_ + c] / cnt - m * m;
        const float inv = 1.0f / sqrtf(v + 1e-4f);
        const float g  = BF ? bl((u32)((const u16*)gamma)[c]) : ((const float*)gamma)[c];
        const float bb = BF ? bl((u32)((const u16*)beta)[c])  : ((const float*)beta)[c];
        sst[t] = g * inv;
        sst[64 + t] = bb - m * (g * inv);
    }
    __syncthreads();

    // ---- apply + store: fully linear 147 KB write per block ----
    #pragma unroll
    for (int q = 0; q < 4; ++q) {
        const int lrow = 4 * wave + q;
        const float scv = sst[lrow], shv = sst[64 + lrow];
        #pragma unroll
        for (int i = 0; i < 3; ++i) {
            const int L = lane + 64 * i;
            if (L < 144) {
                const int n = 4 * L;
                const uint2 pk = Y[i][q];
                float o0 = fmaf(h2f((u16)(pk.x & 0xFFFFu)), scv, shv);
                float o1 = fmaf(h2f((u16)(pk.x >> 16)),     scv, shv);
                float o2 = fmaf(h2f((u16)(pk.y & 0xFFFFu)), scv, shv);
                float o3 = fmaf(h2f((u16)(pk.y >> 16)),     scv, shv);
                o0 = (o0 >= 0.f) ? o0 : 0.2f * o0;
                o1 = (o1 >= 0.f) ? o1 : 0.2f * o1;
                o2 = (o2 >= 0.f) ? o2 : 0.2f * o2;
                o3 = (o3 >= 0.f) ? o3 : 0.2f * o3;
                const u64 ob = (rbase + lrow) * NN + n;
                if (BF) {
                    u32x2 w2;
                    w2.x = (u32)f2b(o0) | ((u32)f2b(o1) << 16);
                    w2.y = (u32)f2b(o2) | ((u32)f2b(o3) << 16);
                    __builtin_nontemporal_store(w2, (u32x2*)((u16*)outv + ob));
                } else {
                    f32x4 w4; w4.x = o0; w4.y = o1; w4.z = o2; w4.w = o3;
                    __builtin_nontemporal_store(w4, (f32x4*)((float*)outv + ob));
                }
            }
        }
    }
}

// ---- fallback: round-7 kernel (proven 74 µs) if cooperative launch fails ----
template<bool BF>
__global__ __launch_bounds__(THREADS, 8) void fused_v7(
        const void* __restrict__ xv, const void* __restrict__ weight,
        const void* __restrict__ gamma, const void* __restrict__ beta,
        void* __restrict__ outv) {
    __shared__ __align__(16) u16 xs[B_ * NN];
    __shared__ float sred[34];
    const int t = threadIdx.x;
    const int ch = ((blockIdx.x & 7) << 6) | (blockIdx.x >> 3);
    const int wave = t >> 6, lane = t & 63;
    const u64 chNN = (u64)ch * NN;

    if (BF) {
        const u16* xb = (const u16*)xv;
        #pragma unroll
        for (int k = 0; k < 5; ++k) {
            const int g = t + THREADS * k;
            if (g < 4608) {
                const int p = g / 72, off = g - 72 * p;
                const uint4 v = *(const uint4*)(xb + (u64)(p * C_ + ch) * NN + 8 * off);
                *(uint4*)(xs + p * NN + 8 * off) = v;
            }
        }
    } else {
        const float* xf = (const float*)xv;
        #pragma unroll
        for (int k = 0; k < 9; ++k) {
            const int g = t + THREADS * k;
            const int p = g / 144, off = g - 144 * p;
            const float4 v = *(const float4*)(xf + (u64)(p * C_ + ch) * NN + 4 * off);
            uint2 pk;
            pk.x = (u32)f2h(v.x) | ((u32)f2h(v.y) << 16);
            pk.y = (u32)f2h(v.z) | ((u32)f2h(v.w) << 16);
            *(uint2*)(xs + p * NN + 4 * off) = pk;
        }
    }
    float4 wr[3];
    #pragma unroll
    for (int i = 0; i < 3; ++i) {
        const int L = lane + 64 * i;
        if (L < 144) {
            const int n = 4 * L;
            if (BF) {
                const uint2 u = *(const uint2*)((const u16*)weight + chNN + n);
                wr[i] = make_float4(bl(u.x), bh(u.x), bl(u.y), bh(u.y));
            } else {
                wr[i] = *(const float4*)((const float*)weight + chNN + n);
            }
        } else wr[i] = make_float4(0.f, 0.f, 0.f, 0.f);
    }
    __syncthreads();
    float s = 0.f, s2 = 0.f;
    uint2 Y[3][4];
    #pragma unroll
    for (int i = 0; i < 3; ++i) {
        const int L = lane + 64 * i;
        if (L < 144) {
            const int n = 4 * L;
            const int r = n / NROW, c0 = n - r * NROW;
            float4 cu, cd, cl, cr;
            {
                const bool up = r > 0, dn = r < NROW - 1;
                cu.x = up ? rdeg(r - 1, c0)     : 0.f;
                cu.y = up ? rdeg(r - 1, c0 + 1) : 0.f;
                cu.z = up ? rdeg(r - 1, c0 + 2) : 0.f;
                cu.w = up ? rdeg(r - 1, c0 + 3) : 0.f;
                cd.x = dn ? rdeg(r + 1, c0)     : 0.f;
                cd.y = dn ? rdeg(r + 1, c0 + 1) : 0.f;
                cd.z = dn ? rdeg(r + 1, c0 + 2) : 0.f;
                cd.w = dn ? rdeg(r + 1, c0 + 3) : 0.f;
                cl.x = (c0 > 0) ? rdeg(r, c0 - 1) : 0.f;
                cl.y = rdeg(r, c0);     cl.z = rdeg(r, c0 + 1);
                cl.w = rdeg(r, c0 + 2); cr.x = rdeg(r, c0 + 1);
                cr.y = rdeg(r, c0 + 2); cr.z = rdeg(r, c0 + 3);
                cr.w = (c0 + 3 < NROW - 1) ? rdeg(r, c0 + 4) : 0.f;
            }
            const int nu = (r > 0)        ? n - NROW : n;
            const int nd = (r < NROW - 1) ? n + NROW : n;
            const int il = (c0 > 0)       ? n - 1    : 0;
            const int ir = (n + 4 < NN)   ? n + 4    : 0;
            const float4 wv = wr[i];
            #pragma unroll
            for (int q = 0; q < 4; ++q) {
                const int p = 4 * wave + q;
                const u16* xp = xs + p * NN;
                const float4 xc = dec4<BF>(xp + n);
                const float4 xu = dec4<BF>(xp + nu);
                const float4 xd = dec4<BF>(xp + nd);
                const float xlm = dec<BF>(xp[il]);
                const float xrp = dec<BF>(xp[ir]);
                const float y0 = (xc.x + cu.x*xu.x + cd.x*xd.x + cl.x*xlm  + cr.x*xc.y) * wv.x;
                const float y1 = (xc.y + cu.y*xu.y + cd.y*xd.y + cl.y*xc.x + cr.y*xc.z) * wv.y;
                const float y2 = (xc.z + cu.z*xu.z + cd.z*xd.z + cl.z*xc.y + cr.z*xc.w) * wv.z;
                const float y3 = (xc.w + cu.w*xu.w + cd.w*xd.w + cl.w*xc.z + cr.w*xrp ) * wv.w;
                s += (y0 + y1) + (y2 + y3);
                s2 = fmaf(y0, y0, s2); s2 = fmaf(y1, y1, s2);
                s2 = fmaf(y2, y2, s2); s2 = fmaf(y3, y3, s2);
                Y[i][q].x = (u32)f2h(y0) | ((u32)f2h(y1) << 16);
                Y[i][q].y = (u32)f2h(y2) | ((u32)f2h(y3) << 16);
            }
        }
    }
    #pragma unroll
    for (int o = 32; o; o >>= 1) {
        s  += __shfl_xor(s,  o, 64);
        s2 += __shfl_xor(s2, o, 64);
    }
    if (lane == 0) { sred[wave] = s; sred[16 + wave] = s2; }
    __syncthreads();
    if (t == 0) {
        float ts = 0.f, tq = 0.f;
        #pragma unroll
        for (int w = 0; w < 16; ++w) { ts += sred[w]; tq += sred[16 + w]; }
        const float cnt = (float)(B_ * NN);
        const float m = ts / cnt;
        const float v = tq / cnt - m * m;
        const float inv = 1.0f / sqrtf(v + 1e-4f);
        const float g  = BF ? bl((u32)((const u16*)gamma)[ch]) : ((const float*)gamma)[ch];
        const float bb = BF ? bl((u32)((const u16*)beta)[ch])  : ((const float*)beta)[ch];
        const float sc = g * inv;
        sred[32] = sc; sred[33] = bb - m * sc;
    }
    __syncthreads();
    const float scv = sred[32], shv = sred[33];
    #pragma unroll
    for (int q = 0; q < 4; ++q) {
        const int p = 4 * wave + q;
        #pragma unroll
        for (int i = 0; i < 3; ++i) {
            const int L = lane + 64 * i;
            if (L < 144) {
                const int n = 4 * L;
                const uint2 pk = Y[i][q];
                float o0 = fmaf(h2f((u16)(pk.x & 0xFFFFu)), scv, shv);
                float o1 = fmaf(h2f((u16)(pk.x >> 16)),     scv, shv);
                float o2 = fmaf(h2f((u16)(pk.y & 0xFFFFu)), scv, shv);
                float o3 = fmaf(h2f((u16)(pk.y >> 16)),     scv, shv);
                o0 = (o0 >= 0.f) ? o0 : 0.2f * o0;
                o1 = (o1 >= 0.f) ? o1 : 0.2f * o1;
                o2 = (o2 >= 0.f) ? o2 : 0.2f * o2;
                o3 = (o3 >= 0.f) ? o3 : 0.2f * o3;
                const u64 ob = (u64)(p * C_ + ch) * NN + n;
                if (BF) {
                    u32x2 w2;
                    w2.x = (u32)f2b(o0) | ((u32)f2b(o1) << 16);
                    w2.y = (u32)f2b(o2) | ((u32)f2b(o3) << 16);
                    __builtin_nontemporal_store(w2, (u32x2*)((u16*)outv + ob));
                } else {
                    f32x4 w4; w4.x = o0; w4.y = o1; w4.z = o2; w4.w = o3;
                    __builtin_nontemporal_store(w4, (f32x4*)((float*)outv + ob));
                }
            }
        }
    }
}

extern "C" void kernel_launch(void* const* d_in, const int* in_sizes, int n_in,
                              void* d_out, int out_size, void* d_ws, size_t ws_size,
                              hipStream_t stream) {
    const void* x      = d_in[0];
    const void* weight = d_in[2];
    const void* gamma  = d_in[3];
    const void* beta   = d_in[4];
    void* outp = d_out;
    float* wsf = (float*)d_ws;
    const long long SZ_BF = (long long)B_ * C_ * NN * 2;
    const bool bf = ((long long)in_sizes[0] == SZ_BF);

    void* args[6] = {(void*)&x, (void*)&weight, (void*)&gamma, (void*)&beta,
                     (void*)&outp, (void*)&wsf};
    hipError_t err;
    if (bf)
        err = hipLaunchCooperativeKernel((void*)fused_v8<true>, dim3(GRID),
                                         dim3(THREADS), args, 0, stream);
    else
        err = hipLaunchCooperativeKernel((void*)fused_v8<false>, dim3(GRID),
                                         dim3(THREADS), args, 0, stream);
    if (err != hipSuccess) {   // cooperative not available: proven fallback
        if (bf)
            fused_v7<true><<<C_, THREADS, 0, stream>>>(x, weight, gamma, beta, d_out);
        else
            fused_v7<false><<<C_, THREADS, 0, stream>>>(x, weight, gamma, beta, d_out);
    }
}

// Round 9
// 198.796 us; speedup vs baseline: 1.8078x; 1.8078x over previous
//
#include <hip/hip_runtime.h>

typedef unsigned short u16;
typedef unsigned int u32;
typedef unsigned long long u64;

#define B_    64
#define C_    512
#define NN    576          // 24*24 nodes
#define NROWP 24           // grid side
#define TPB   256          // 4 waves/block, wave per row
#define NROWS (B_*C_)      // 32768 rows
#define GRIDN (NROWS/4)    // 8192 blocks

__device__ __forceinline__ float bl(u32 u) {            // low bf16 -> f32
    union { u32 i; float f; } v; v.i = u << 16; return v.f;
}
__device__ __forceinline__ u16 f2b(float f) {           // f32 -> bf16 RNE
    union { float f; u32 i; } v; v.f = f;
    u32 x = v.i;
    x += 0x7fffu + ((x >> 16) & 1u);
    return (u16)(x >> 16);
}

// 1/deg of grid node (r,c); deg in {2,3,4}. 1.0f/3.0f bit-matches the
// reference's float64->float32 cast, so geometric coefs are EXACT vs adj.
__device__ __forceinline__ float rdeg(int r, int c) {
    const int d = (r > 0) + (r < NROWP - 1) + (c > 0) + (c < NROWP - 1);
    return d == 4 ? 0.25f : (d == 3 ? (1.0f / 3.0f) : 0.5f);
}

// One wave owns one (batch,channel) row of 576 nodes: lane holds m[j] =
// x[lane + 64j], j=0..8. Stencil neighbors (l-1, l+1, l-24, l+24) come from
// cross-lane shuffles of m[j] / m[j±1] — no LDS at all. Out-of-grid
// neighbors multiply a 0 coefficient, so fallback shuffle values are safe.
template<bool BF>
__device__ __forceinline__ void row_y(const void* __restrict__ xrow,
                                      const void* __restrict__ wrow,
                                      int lane, float* y) {
    float m[9];
    #pragma unroll
    for (int j = 0; j < 9; ++j)
        m[j] = BF ? bl((u32)((const u16*)xrow)[lane + 64 * j])
                  : ((const float*)xrow)[lane + 64 * j];

    float al = __shfl(m[0], (lane + 63) & 63, 64);   // x[l-1]  candidate
    float au = __shfl(m[0], (lane + 40) & 63, 64);   // x[l-24] candidate
    float ar = __shfl(m[0], (lane + 1) & 63, 64);    // x[l+1]  candidate
    float ad = __shfl(m[0], (lane + 24) & 63, 64);   // x[l+24] candidate
    float alP = al, auP = au;                        // j-1 values
    #pragma unroll
    for (int j = 0; j < 9; ++j) {
        const int l = lane + 64 * j;
        const int r = l / NROWP, col = l - r * NROWP;
        float arN, adN, alN, auN;                    // j+1 values
        if (j < 8) {
            arN = __shfl(m[j + 1], (lane + 1) & 63, 64);
            adN = __shfl(m[j + 1], (lane + 24) & 63, 64);
            alN = __shfl(m[j + 1], (lane + 63) & 63, 64);
            auN = __shfl(m[j + 1], (lane + 40) & 63, 64);
        } else { arN = ar; adN = ad; alN = al; auN = au; }
        // cross-register boundary lanes pick the j-1 / j+1 shuffle
        const float xl = (lane == 0)  ? alP : al;    // x[64j-1] for lane 0
        const float xu = (lane < 24)  ? auP : au;    // from m[j-1]
        const float xr = (lane == 63) ? arN : ar;    // from m[j+1]
        const float xd = (lane >= 40) ? adN : ad;    // from m[j+1]
        const float cu = (r > 0)         ? rdeg(r - 1, col) : 0.f;
        const float cd = (r < NROWP - 1) ? rdeg(r + 1, col) : 0.f;
        const float cl = (col > 0)       ? rdeg(r, col - 1) : 0.f;
        const float cr = (col < NROWP-1) ? rdeg(r, col + 1) : 0.f;
        const float w = BF ? bl((u32)((const u16*)wrow)[l])
                           : ((const float*)wrow)[l];
        // diagonal coef of D^-1 A + I is exactly 1.0 -> center term is m[j]
        y[j] = (m[j] + cu * xu + cd * xd + cl * xl + cr * xr) * w;
        alP = al; auP = au; al = alN; au = auN; ar = arN; ad = adN;
    }
}

__global__ void zero_ws(float* __restrict__ ws) {
    ws[threadIdx.x] = 0.f;                           // 1024 floats
}

// Pass 1: pure linear stream over x, per-channel sums via 2 atomics/row.
template<bool BF>
__global__ __launch_bounds__(TPB, 8) void gcn_stats(
        const void* __restrict__ xv, const void* __restrict__ wv,
        float* __restrict__ ws) {
    const int wave = threadIdx.x >> 6, lane = threadIdx.x & 63;
    const int row = (blockIdx.x << 2) + wave;        // = b*512 + ch
    const int ch = row & (C_ - 1);
    const void* xrow = BF ? (const void*)((const u16*)xv + (u64)row * NN)
                          : (const void*)((const float*)xv + (u64)row * NN);
    const void* wrow = BF ? (const void*)((const u16*)wv + (u64)ch * NN)
                          : (const void*)((const float*)wv + (u64)ch * NN);
    float y[9];
    row_y<BF>(xrow, wrow, lane, y);
    float s = 0.f, s2 = 0.f;
    #pragma unroll
    for (int j = 0; j < 9; ++j) { s += y[j]; s2 = fmaf(y[j], y[j], s2); }
    #pragma unroll
    for (int o = 32; o; o >>= 1) {
        s  += __shfl_xor(s,  o, 64);
        s2 += __shfl_xor(s2, o, 64);
    }
    if (lane == 0) {
        atomicAdd(&ws[ch], s);
        atomicAdd(&ws[C_ + ch], s2);
    }
}

// Pass 2: recompute y (x is L2/L3-warm), finalize scale/shift per wave from
// the 4 KB stats table, apply affine + LeakyReLU, linear coalesced store.
template<bool BF>
__global__ __launch_bounds__(TPB, 8) void gcn_apply(
        const void* __restrict__ xv, const void* __restrict__ wv,
        const void* __restrict__ gv, const void* __restrict__ bv,
        const float* __restrict__ ws, void* __restrict__ outv) {
    const int wave = threadIdx.x >> 6, lane = threadIdx.x & 63;
    const int row = (blockIdx.x << 2) + wave;
    const int ch = row & (C_ - 1);
    const void* xrow = BF ? (const void*)((const u16*)xv + (u64)row * NN)
                          : (const void*)((const float*)xv + (u64)row * NN);
    const void* wrow = BF ? (const void*)((const u16*)wv + (u64)ch * NN)
                          : (const void*)((const float*)wv + (u64)ch * NN);
    const float cnt = (float)(B_ * NN);
    const float mean = ws[ch] / cnt;                 // broadcast loads
    const float var  = ws[C_ + ch] / cnt - mean * mean;
    const float inv = 1.0f / sqrtf(var + 1e-4f);
    const float g  = BF ? bl((u32)((const u16*)gv)[ch]) : ((const float*)gv)[ch];
    const float bb = BF ? bl((u32)((const u16*)bv)[ch]) : ((const float*)bv)[ch];
    const float scv = g * inv, shv = bb - mean * scv;

    float y[9];
    row_y<BF>(xrow, wrow, lane, y);
    #pragma unroll
    for (int j = 0; j < 9; ++j) {
        float o = fmaf(y[j], scv, shv);
        o = (o >= 0.f) ? o : 0.2f * o;               // LeakyReLU(0.2)
        const u64 idx = (u64)row * NN + lane + 64 * j;
        if (BF) ((u16*)outv)[idx] = f2b(o);
        else    ((float*)outv)[idx] = o;
    }
}

extern "C" void kernel_launch(void* const* d_in, const int* in_sizes, int n_in,
                              void* d_out, int out_size, void* d_ws, size_t ws_size,
                              hipStream_t stream) {
    const void* x      = d_in[0];
    const void* weight = d_in[2];
    const void* gamma  = d_in[3];
    const void* beta   = d_in[4];
    float* wsf = (float*)d_ws;
    const long long SZ_BF = (long long)B_ * C_ * NN * 2;
    const bool bf = ((long long)in_sizes[0] == SZ_BF);

    zero_ws<<<1, 1024, 0, stream>>>(wsf);
    if (bf) {
        gcn_stats<true><<<GRIDN, TPB, 0, stream>>>(x, weight, wsf);
        gcn_apply<true><<<GRIDN, TPB, 0, stream>>>(x, weight, gamma, beta, wsf, d_out);
    } else {
        gcn_stats<false><<<GRIDN, TPB, 0, stream>>>(x, weight, wsf);
        gcn_apply<false><<<GRIDN, TPB, 0, stream>>>(x, weight, gamma, beta, wsf, d_out);
    }
}